// Round 1
// baseline (1074.697 us; speedup 1.0000x reference)
//
#include <hip/hip_runtime.h>

#define NPIX (512 * 512)
#define BLK 256

#define SCAN_T 256
#define SCAN_E 8
#define SCAN_CHUNK (SCAN_T * SCAN_E)  // 2048

#define TOTB (NPIX * 6)
#define TOTS (NPIX * 3)
#define TOTE (NPIX * 9)

typedef _Float16 h4 __attribute__((ext_vector_type(4)));

constexpr float ALPHA_B = 32.0f / 33.0f;   // 1/(1+2^-5)
constexpr float ALPHA_S = 0.8f;            // 1/(1+2^-2)
constexpr float BI_COMPAT = 10.0f;
constexpr float SP_COMPAT = 3.0f;

// 4-byte CSR entry: [31:18] = weight (14-bit fixed point, /16383), [17:0] = pixel id
__device__ __forceinline__ unsigned pack_ent(int n, float w) {
    float wc = fminf(fmaxf(w, 0.f), 1.f);
    unsigned iw = (unsigned)(wc * 16383.f + 0.5f);
    return (iw << 18) | (unsigned)n;
}
__device__ __forceinline__ int ent_pix(unsigned e) { return (int)(e & 0x3FFFFu); }
__device__ __forceinline__ float ent_w(unsigned e) {
    return (float)(e >> 18) * (1.0f / 16383.0f);
}

__device__ __forceinline__ float4 f4zero() { return make_float4(0.f, 0.f, 0.f, 0.f); }
__device__ __forceinline__ h4 h4zero() {
    h4 z; z.x = (_Float16)0.f; z.y = (_Float16)0.f; z.z = (_Float16)0.f; z.w = (_Float16)0.f;
    return z;
}

// ---------------- softmax init (fallback path) ----------------
__global__ void k_softmax_init(const float4* __restrict__ u, float4* __restrict__ Q) {
    int n = blockIdx.x * BLK + threadIdx.x;
    if (n >= NPIX) return;
    float4 uu = u[n];
    float l0 = -uu.x, l1 = -uu.y, l2 = -uu.z, l3 = -uu.w;
    float m = fmaxf(fmaxf(l0, l1), fmaxf(l2, l3));
    float e0 = expf(l0 - m), e1 = expf(l1 - m), e2 = expf(l2 - m), e3 = expf(l3 - m);
    float inv = 1.0f / (e0 + e1 + e2 + e3);
    Q[n] = make_float4(e0 * inv, e1 * inv, e2 * inv, e3 * inv);
}

// ---------------- fused count + linked-list build + softmax init ----------------
// cnt/head are concatenated over both lattices: bilateral o in [0,Vb), spatial Vb+o.
// Entry ids: bilateral e = n*6+r in [0,TOTB); spatial e = TOTB + n*3+r.
// next[e] = previous list element (or -1). Safe: next is only read in k_compact
// (after the dispatch boundary), so no intra-kernel ordering is required.
__global__ void k_count_link_softmax(const int* __restrict__ osb, const int* __restrict__ oss,
                                     int* __restrict__ cnt, int* __restrict__ head,
                                     int* __restrict__ next,
                                     const float4* __restrict__ u, float4* __restrict__ Q,
                                     int Vb) {
    int n = blockIdx.x * BLK + threadIdx.x;
    if (n >= NPIX) return;
    float4 uu = u[n];
    float l0 = -uu.x, l1 = -uu.y, l2 = -uu.z, l3 = -uu.w;
    float m = fmaxf(fmaxf(l0, l1), fmaxf(l2, l3));
    float e0 = expf(l0 - m), e1 = expf(l1 - m), e2 = expf(l2 - m), e3 = expf(l3 - m);
    float inv = 1.0f / (e0 + e1 + e2 + e3);
    Q[n] = make_float4(e0 * inv, e1 * inv, e2 * inv, e3 * inv);
#pragma unroll
    for (int r = 0; r < 6; r++) {
        int o = osb[n * 6 + r];
        int e = n * 6 + r;
        atomicAdd(&cnt[o], 1);
        next[e] = atomicExch(&head[o], e);
    }
#pragma unroll
    for (int r = 0; r < 3; r++) {
        int o = Vb + oss[n * 3 + r];
        int e = TOTB + n * 3 + r;
        atomicAdd(&cnt[o], 1);
        next[e] = atomicExch(&head[o], e);
    }
}

// ---------------- scan (over concatenated counts, V = Vb+Vs) ----------------
__global__ void k_chunk_sum(const int* __restrict__ counts, int V, int* __restrict__ csum) {
    __shared__ int lds[SCAN_T];
    int base = blockIdx.x * SCAN_CHUNK;
    int s = 0;
#pragma unroll
    for (int j = 0; j < SCAN_E; j++) {
        int idx = base + threadIdx.x * SCAN_E + j;
        if (idx < V) s += counts[idx];
    }
    lds[threadIdx.x] = s;
    __syncthreads();
    for (int off = SCAN_T / 2; off > 0; off >>= 1) {
        if ((int)threadIdx.x < off) lds[threadIdx.x] += lds[threadIdx.x + off];
        __syncthreads();
    }
    if (threadIdx.x == 0) csum[blockIdx.x] = lds[0];
}

__global__ void k_scan_csum(int* __restrict__ csum, int nchunks) {
    __shared__ int lds[SCAN_T];
    int carry = 0;
    for (int base = 0; base < nchunks; base += SCAN_T) {
        int idx = base + threadIdx.x;
        int v = (idx < nchunks) ? csum[idx] : 0;
        lds[threadIdx.x] = v;
        __syncthreads();
        for (int off = 1; off < SCAN_T; off <<= 1) {
            int t = ((int)threadIdx.x >= off) ? lds[threadIdx.x - off] : 0;
            __syncthreads();
            lds[threadIdx.x] += t;
            __syncthreads();
        }
        int incl = lds[threadIdx.x];
        int tile_total = lds[SCAN_T - 1];
        if (idx < nchunks) csum[idx] = incl - v + carry;  // exclusive
        carry += tile_total;
        __syncthreads();
    }
}

__global__ void k_chunk_scan(const int* __restrict__ counts, int V,
                             const int* __restrict__ csum, int* __restrict__ start) {
    __shared__ int lds[SCAN_T];
    int base = blockIdx.x * SCAN_CHUNK;
    int local[SCAN_E];
    int s = 0;
#pragma unroll
    for (int j = 0; j < SCAN_E; j++) {
        int idx = base + threadIdx.x * SCAN_E + j;
        int c = (idx < V) ? counts[idx] : 0;
        local[j] = c;
        s += c;
    }
    lds[threadIdx.x] = s;
    __syncthreads();
    for (int off = 1; off < SCAN_T; off <<= 1) {
        int t = ((int)threadIdx.x >= off) ? lds[threadIdx.x - off] : 0;
        __syncthreads();
        lds[threadIdx.x] += t;
        __syncthreads();
    }
    int excl = lds[threadIdx.x] - s + csum[blockIdx.x];
#pragma unroll
    for (int j = 0; j < SCAN_E; j++) {
        int idx = base + threadIdx.x * SCAN_E + j;
        if (idx < V) start[idx] = excl;
        excl += local[j];
    }
}

// ---------------- CSR compaction (replaces the scatter-fill) ----------------
// Per vertex: walk the linked list, emitting packed entries densely at start[o].
// Writes are vertex-major & contiguous -> coalesced (vs 12x write amplification
// of the old scattered dword fill).
__global__ void k_compact(const int* __restrict__ head, const int* __restrict__ next,
                          const int* __restrict__ start,
                          const float* __restrict__ wsb, const float* __restrict__ wss,
                          unsigned* __restrict__ ent, int V, int Vb) {
    int o = blockIdx.x * BLK + threadIdx.x;
    if (o >= V) return;
    int p = start[o];
    int e = head[o];
    if (o < Vb) {
        while (e >= 0) {
            unsigned n = (unsigned)e / 6u;   // wsb is pixel-major: wsb[e] is the weight
            ent[p++] = pack_ent((int)n, wsb[e]);
            e = next[e];
        }
    } else {
        while (e >= 0) {
            int ee = e - TOTB;
            unsigned n = (unsigned)ee / 3u;
            ent[p++] = pack_ent((int)n, wss[ee]);
            e = next[e];
        }
    }
}

// ---------------- gather-based splat (single concatenated CSR) ----------------
__global__ void k_gather1_both(const unsigned* __restrict__ ent, const int* __restrict__ start,
                               int V, int Vb,
                               float* __restrict__ nB, float* __restrict__ nS) {
    int i = blockIdx.x * BLK + threadIdx.x;
    if (i >= V) return;
    int s = start[i];
    int e = (i + 1 < V) ? start[i + 1] : TOTE;
    float acc = 0.f;
    for (int k = s; k < e; k++) acc += ent_w(ent[k]);
    if (i < Vb) nB[i] = acc;
    else nS[i - Vb] = acc;
}

__global__ void k_gather4h_both(const unsigned* __restrict__ ent, const int* __restrict__ start,
                                int V, int Vb,
                                h4* __restrict__ tB, h4* __restrict__ tS,
                                const float4* __restrict__ Q) {
    int i = blockIdx.x * BLK + threadIdx.x;
    if (i >= V) return;
    int s = start[i];
    int e = (i + 1 < V) ? start[i + 1] : TOTE;
    float ax = 0.f, ay = 0.f, az = 0.f, aw = 0.f;
    for (int k = s; k < e; k++) {
        unsigned en = ent[k];
        float w = ent_w(en);
        float4 q = Q[ent_pix(en)];
        ax += w * q.x; ay += w * q.y; az += w * q.z; aw += w * q.w;
    }
    h4 h;
    h.x = (_Float16)ax; h.y = (_Float16)ay; h.z = (_Float16)az; h.w = (_Float16)aw;
    if (i < Vb) tB[i] = h;
    else tS[i - Vb] = h;
}

// ---------------- blur ----------------
__global__ void k_blur1(const float* __restrict__ in, float* __restrict__ out,
                        const int* __restrict__ bn, int M) {
    int i = blockIdx.x * BLK + threadIdx.x;
    if (i > M) return;
    if (i == 0) { out[0] = 0.f; return; }
    int n1 = bn[(size_t)(i - 1) * 2 + 0];
    int n2 = bn[(size_t)(i - 1) * 2 + 1];
    out[i] = in[i] + 0.5f * (in[n1] + in[n2]);
}

__global__ void k_blur1_both(const float* __restrict__ inB, float* __restrict__ outB,
                             const int* __restrict__ bnB, int Mb,
                             const float* __restrict__ inS, float* __restrict__ outS,
                             const int* __restrict__ bnS, int Ms) {
    int i = blockIdx.x * BLK + threadIdx.x;
    const float* in; float* out; const int* bn; int M, idx;
    if (i <= Mb) { in = inB; out = outB; bn = bnB; M = Mb; idx = i; }
    else {
        idx = i - (Mb + 1);
        if (idx > Ms) return;
        in = inS; out = outS; bn = bnS; M = Ms;
    }
    if (idx == 0) { out[0] = 0.f; return; }
    int n1 = bn[(size_t)(idx - 1) * 2 + 0];
    int n2 = bn[(size_t)(idx - 1) * 2 + 1];
    out[idx] = in[idx] + 0.5f * (in[n1] + in[n2]);
}

__global__ void k_blur4h(const h4* __restrict__ in, h4* __restrict__ out,
                         const int* __restrict__ bn, int M) {
    int i = blockIdx.x * BLK + threadIdx.x;
    if (i > M) return;
    if (i == 0) { out[0] = h4zero(); return; }
    int n1 = bn[(size_t)(i - 1) * 2 + 0];
    int n2 = bn[(size_t)(i - 1) * 2 + 1];
    h4 a = in[i], b = in[n1], c = in[n2];
    h4 o;
    o.x = (_Float16)((float)a.x + 0.5f * ((float)b.x + (float)c.x));
    o.y = (_Float16)((float)a.y + 0.5f * ((float)b.y + (float)c.y));
    o.z = (_Float16)((float)a.z + 0.5f * ((float)b.z + (float)c.z));
    o.w = (_Float16)((float)a.w + 0.5f * ((float)b.w + (float)c.w));
    out[i] = o;
}

__global__ void k_blur4h_both(const h4* __restrict__ inB, h4* __restrict__ outB,
                              const int* __restrict__ bnB, int Mb,
                              const h4* __restrict__ inS, h4* __restrict__ outS,
                              const int* __restrict__ bnS, int Ms) {
    int i = blockIdx.x * BLK + threadIdx.x;
    const h4* in; h4* out; const int* bn; int M, idx;
    if (i <= Mb) { in = inB; out = outB; bn = bnB; M = Mb; idx = i; }
    else {
        idx = i - (Mb + 1);
        if (idx > Ms) return;
        in = inS; out = outS; bn = bnS; M = Ms;
    }
    if (idx == 0) { out[0] = h4zero(); return; }
    int n1 = bn[(size_t)(idx - 1) * 2 + 0];
    int n2 = bn[(size_t)(idx - 1) * 2 + 1];
    h4 a = in[idx], b = in[n1], c = in[n2];
    h4 o;
    o.x = (_Float16)((float)a.x + 0.5f * ((float)b.x + (float)c.x));
    o.y = (_Float16)((float)a.y + 0.5f * ((float)b.y + (float)c.y));
    o.z = (_Float16)((float)a.z + 0.5f * ((float)b.z + (float)c.z));
    o.w = (_Float16)((float)a.w + 0.5f * ((float)b.w + (float)c.w));
    out[idx] = o;
}

// ---------------- normalizer slice + weight prescale ----------------
__global__ void k_norm_prescale(const float* __restrict__ nTb, const float* __restrict__ wsb,
                                const int* __restrict__ osb,
                                const float* __restrict__ nTs, const float* __restrict__ wss,
                                const int* __restrict__ oss,
                                float* __restrict__ wsbp, float* __restrict__ wssp) {
    int n = blockIdx.x * BLK + threadIdx.x;
    if (n >= NPIX) return;
    float sb = 0.f;
#pragma unroll
    for (int r = 0; r < 6; r++) sb += wsb[n * 6 + r] * nTb[osb[n * 6 + r]];
    float cb = BI_COMPAT * ALPHA_B / (ALPHA_B * sb + 1e-20f);
#pragma unroll
    for (int r = 0; r < 6; r++) wsbp[n * 6 + r] = wsb[n * 6 + r] * cb;
    float ss = 0.f;
#pragma unroll
    for (int r = 0; r < 3; r++) ss += wss[n * 3 + r] * nTs[oss[n * 3 + r]];
    float cs = SP_COMPAT * ALPHA_S / (ALPHA_S * ss + 1e-20f);
#pragma unroll
    for (int r = 0; r < 3; r++) wssp[n * 3 + r] = wss[n * 3 + r] * cs;
}

// ---------------- fused slice + message + softmax ----------------
__global__ void k_slice_combine_h(const float4* __restrict__ u,
                                  const h4* __restrict__ tb, const float* __restrict__ wsbp,
                                  const int* __restrict__ osb,
                                  const h4* __restrict__ ts, const float* __restrict__ wssp,
                                  const int* __restrict__ oss,
                                  float4* __restrict__ Qout) {
    int n = blockIdx.x * BLK + threadIdx.x;
    if (n >= NPIX) return;
    float4 uu = u[n];
    float l0 = -uu.x, l1 = -uu.y, l2 = -uu.z, l3 = -uu.w;
#pragma unroll
    for (int r = 0; r < 6; r++) {
        float w = wsbp[n * 6 + r];
        h4 t = tb[osb[n * 6 + r]];
        l0 += w * (float)t.x; l1 += w * (float)t.y; l2 += w * (float)t.z; l3 += w * (float)t.w;
    }
#pragma unroll
    for (int r = 0; r < 3; r++) {
        float w = wssp[n * 3 + r];
        h4 t = ts[oss[n * 3 + r]];
        l0 += w * (float)t.x; l1 += w * (float)t.y; l2 += w * (float)t.z; l3 += w * (float)t.w;
    }
    float m = fmaxf(fmaxf(l0, l1), fmaxf(l2, l3));
    float e0 = expf(l0 - m), e1 = expf(l1 - m), e2 = expf(l2 - m), e3 = expf(l3 - m);
    float inv = 1.0f / (e0 + e1 + e2 + e3);
    Qout[n] = make_float4(e0 * inv, e1 * inv, e2 * inv, e3 * inv);
}

// ---------------- fallback (fp32 atomic splat path) ----------------
template <int D1>
__global__ void k_splat1(const float* __restrict__ ws, const int* __restrict__ os,
                         float* __restrict__ table) {
    int n = blockIdx.x * BLK + threadIdx.x;
    if (n >= NPIX) return;
#pragma unroll
    for (int r = 0; r < D1; r++) atomicAdd(&table[os[n * D1 + r]], ws[n * D1 + r]);
}

template <int D1>
__global__ void k_splat4(const float4* __restrict__ Q, const float* __restrict__ ws,
                         const int* __restrict__ os, float* __restrict__ table) {
    int n = blockIdx.x * BLK + threadIdx.x;
    if (n >= NPIX) return;
    float4 q = Q[n];
#pragma unroll
    for (int r = 0; r < D1; r++) {
        float w = ws[n * D1 + r];
        int o = os[n * D1 + r];
        float* t = table + 4 * (size_t)o;
        atomicAdd(t + 0, q.x * w);
        atomicAdd(t + 1, q.y * w);
        atomicAdd(t + 2, q.z * w);
        atomicAdd(t + 3, q.w * w);
    }
}

__global__ void k_blur4(const float4* __restrict__ in, float4* __restrict__ out,
                        const int* __restrict__ bn, int M) {
    int i = blockIdx.x * BLK + threadIdx.x;
    if (i > M) return;
    if (i == 0) { out[0] = f4zero(); return; }
    int n1 = bn[(size_t)(i - 1) * 2 + 0];
    int n2 = bn[(size_t)(i - 1) * 2 + 1];
    float4 a = in[i], b = in[n1], c = in[n2];
    out[i] = make_float4(a.x + 0.5f * (b.x + c.x), a.y + 0.5f * (b.y + c.y),
                         a.z + 0.5f * (b.z + c.z), a.w + 0.5f * (b.w + c.w));
}

template <int D1>
__global__ void k_norm_slice(const float* __restrict__ table, const float* __restrict__ ws,
                             const int* __restrict__ os, float alpha,
                             float* __restrict__ inv_out) {
    int n = blockIdx.x * BLK + threadIdx.x;
    if (n >= NPIX) return;
    float s = 0.f;
#pragma unroll
    for (int r = 0; r < D1; r++) s += ws[n * D1 + r] * table[os[n * D1 + r]];
    inv_out[n] = 1.0f / (alpha * s + 1e-20f);
}

__global__ void k_slice_combine(const float4* __restrict__ u,
                                const float4* __restrict__ tb, const float* __restrict__ wsb,
                                const int* __restrict__ osb,
                                const float4* __restrict__ ts, const float* __restrict__ wss,
                                const int* __restrict__ oss,
                                const float* __restrict__ inv_nb,
                                const float* __restrict__ inv_ns,
                                float4* __restrict__ Qout) {
    int n = blockIdx.x * BLK + threadIdx.x;
    if (n >= NPIX) return;
    float4 ab = f4zero();
#pragma unroll
    for (int r = 0; r < 6; r++) {
        float w = wsb[n * 6 + r];
        float4 t = tb[osb[n * 6 + r]];
        ab.x += w * t.x; ab.y += w * t.y; ab.z += w * t.z; ab.w += w * t.w;
    }
    float4 as = f4zero();
#pragma unroll
    for (int r = 0; r < 3; r++) {
        float w = wss[n * 3 + r];
        float4 t = ts[oss[n * 3 + r]];
        as.x += w * t.x; as.y += w * t.y; as.z += w * t.z; as.w += w * t.w;
    }
    float cb = BI_COMPAT * ALPHA_B * inv_nb[n];
    float cs = SP_COMPAT * ALPHA_S * inv_ns[n];
    float4 uu = u[n];
    float l0 = -uu.x + cb * ab.x + cs * as.x;
    float l1 = -uu.y + cb * ab.y + cs * as.y;
    float l2 = -uu.z + cb * ab.z + cs * as.z;
    float l3 = -uu.w + cb * ab.w + cs * as.w;
    float m = fmaxf(fmaxf(l0, l1), fmaxf(l2, l3));
    float e0 = expf(l0 - m), e1 = expf(l1 - m), e2 = expf(l2 - m), e3 = expf(l3 - m);
    float inv = 1.0f / (e0 + e1 + e2 + e3);
    Qout[n] = make_float4(e0 * inv, e1 * inv, e2 * inv, e3 * inv);
}

extern "C" void kernel_launch(void* const* d_in, const int* in_sizes, int n_in,
                              void* d_out, int out_size, void* d_ws, size_t ws_size,
                              hipStream_t stream) {
    const float* unary = (const float*)d_in[0];
    const float* wsb   = (const float*)d_in[1];
    const int*   osb   = (const int*)d_in[2];
    const int*   bnb   = (const int*)d_in[3];
    const float* wss   = (const float*)d_in[5];
    const int*   oss   = (const int*)d_in[6];
    const int*   bns   = (const int*)d_in[7];
    const int Mb = in_sizes[3] / 12;   // bn_b is (6, Mb, 2)
    const int Ms = in_sizes[7] / 6;    // bn_s is (3, Ms, 2)
    const int Vb = Mb + 1, Vs = Ms + 1;
    const int V = Vb + Vs;

    float* Q = (float*)d_out;  // N x 4, final value IS the output

    char* p = (char*)d_ws;
    auto alloc = [&](size_t nbytes) -> void* {
        void* r = (void*)p;
        p += (nbytes + 15) & ~(size_t)15;
        return r;
    };
    h4*   tAb  = (h4*)alloc((size_t)Vb * 8);
    h4*   tBb  = (h4*)alloc((size_t)Vb * 8);
    h4*   tAs  = (h4*)alloc((size_t)Vs * 8);
    h4*   tBs  = (h4*)alloc((size_t)Vs * 8);
    float* nAb = (float*)alloc((size_t)Vb * 4);
    float* nBb = (float*)alloc((size_t)Vb * 4);
    float* nAs = (float*)alloc((size_t)Vs * 4);
    float* nBs = (float*)alloc((size_t)Vs * 4);
    // wsbp (6N floats) and wssp (3N floats) are contiguous (6N*4 is 16B-aligned);
    // the 9N-int `next` array aliases them: next is dead before k_norm_prescale
    // writes wsbp/wssp, and wsbp/wssp are only read after that.
    float* wsbp = (float*)alloc((size_t)NPIX * 6 * 4);
    float* wssp = (float*)alloc((size_t)NPIX * 3 * 4);
    int*   next = (int*)wsbp;
    int*  start = (int*)alloc((size_t)V * 4);
    int*  cnt   = (int*)alloc((size_t)V * 4);
    int*  head  = (int*)alloc((size_t)V * 4);
    unsigned* ent = (unsigned*)alloc((size_t)TOTE * 4);
    int*  csum  = (int*)alloc(8192 * 4);
    size_t need = (size_t)(p - (char*)d_ws);
    bool use_gather = need <= ws_size;

    dim3 blk(BLK);
    dim3 gN((NPIX + BLK - 1) / BLK);
    dim3 gVb((Vb + BLK - 1) / BLK);
    dim3 gV((V + BLK - 1) / BLK);

    if (use_gather) {
        // ---- build CSR via linked-list inversion + compaction ----
        int nch = (V + SCAN_CHUNK - 1) / SCAN_CHUNK;
        hipMemsetAsync(cnt, 0, (size_t)V * 4, stream);
        hipMemsetAsync(head, 0xFF, (size_t)V * 4, stream);  // -1 sentinel
        k_count_link_softmax<<<gN, blk, 0, stream>>>(osb, oss, cnt, head, next,
                                                     (const float4*)unary, (float4*)Q, Vb);
        k_chunk_sum<<<dim3(nch), dim3(SCAN_T), 0, stream>>>(cnt, V, csum);
        k_scan_csum<<<dim3(1), dim3(SCAN_T), 0, stream>>>(csum, nch);
        k_chunk_scan<<<dim3(nch), dim3(SCAN_T), 0, stream>>>(cnt, V, csum, start);
        k_compact<<<gV, blk, 0, stream>>>(head, next, start, wsb, wss, ent, V, Vb);

        // ---- normalizers (fp32, C=1), then prescale slice weights ----
        k_gather1_both<<<gV, blk, 0, stream>>>(ent, start, V, Vb, nAb, nAs);
        {
            float* a = nAb; float* b = nBb;
            float* as_ = nAs; float* bs_ = nBs;
            for (int j = 0; j < 3; j++) {
                k_blur1_both<<<gV, blk, 0, stream>>>(a, b, bnb + (size_t)j * Mb * 2, Mb,
                                                     as_, bs_, bns + (size_t)j * Ms * 2, Ms);
                float* t = a; a = b; b = t;
                t = as_; as_ = bs_; bs_ = t;
            }
            for (int j = 3; j < 6; j++) {
                k_blur1<<<gVb, blk, 0, stream>>>(a, b, bnb + (size_t)j * Mb * 2, Mb);
                float* t = a; a = b; b = t;
            }
            // bilateral final in a (= nAb), spatial final in as_ (= nBs)
            k_norm_prescale<<<gN, blk, 0, stream>>>(a, wsb, osb, as_, wss, oss, wsbp, wssp);
        }

        // ---- 10 mean-field iterations ----
        for (int it = 0; it < 10; it++) {
            k_gather4h_both<<<gV, blk, 0, stream>>>(ent, start, V, Vb, tAb, tAs,
                                                    (const float4*)Q);
            h4* a = tAb; h4* b = tBb;
            h4* as_ = tAs; h4* bs_ = tBs;
            for (int j = 0; j < 3; j++) {
                k_blur4h_both<<<gV, blk, 0, stream>>>(a, b, bnb + (size_t)j * Mb * 2, Mb,
                                                      as_, bs_, bns + (size_t)j * Ms * 2, Ms);
                h4* t = a; a = b; b = t;
                t = as_; as_ = bs_; bs_ = t;
            }
            for (int j = 3; j < 6; j++) {
                k_blur4h<<<gVb, blk, 0, stream>>>(a, b, bnb + (size_t)j * Mb * 2, Mb);
                h4* t = a; a = b; b = t;
            }
            // bilateral final in a (= tAb), spatial final in as_ (= tBs)
            k_slice_combine_h<<<gN, blk, 0, stream>>>((const float4*)unary,
                                                      a, wsbp, osb, as_, wssp, oss,
                                                      (float4*)Q);
        }
    } else {
        // ---- fallback: fp32 atomic splat path ----
        char* q = (char*)d_ws;
        auto alloc2 = [&](size_t nbytes) -> void* {
            void* r = (void*)q;
            q += (nbytes + 15) & ~(size_t)15;
            return r;
        };
        float* fAb = (float*)alloc2((size_t)Vb * 4 * sizeof(float));
        float* fBb = (float*)alloc2((size_t)Vb * 4 * sizeof(float));
        float* fAs = (float*)alloc2((size_t)Vs * 4 * sizeof(float));
        float* fBs = (float*)alloc2((size_t)Vs * 4 * sizeof(float));
        float* inv_nb = (float*)alloc2(NPIX * sizeof(float));
        float* inv_ns = (float*)alloc2(NPIX * sizeof(float));
        dim3 gMb((Mb + 1 + BLK - 1) / BLK);
        dim3 gMs((Ms + 1 + BLK - 1) / BLK);

        hipMemsetAsync(fAb, 0, (size_t)Vb * sizeof(float), stream);
        k_splat1<6><<<gN, blk, 0, stream>>>(wsb, osb, fAb);
        {
            float* a = fAb; float* b = fBb;
            for (int j = 0; j < 6; j++) {
                k_blur1<<<gMb, blk, 0, stream>>>(a, b, bnb + (size_t)j * Mb * 2, Mb);
                float* t = a; a = b; b = t;
            }
            k_norm_slice<6><<<gN, blk, 0, stream>>>(a, wsb, osb, ALPHA_B, inv_nb);
        }
        hipMemsetAsync(fAs, 0, (size_t)Vs * sizeof(float), stream);
        k_splat1<3><<<gN, blk, 0, stream>>>(wss, oss, fAs);
        {
            float* a = fAs; float* b = fBs;
            for (int j = 0; j < 3; j++) {
                k_blur1<<<gMs, blk, 0, stream>>>(a, b, bns + (size_t)j * Ms * 2, Ms);
                float* t = a; a = b; b = t;
            }
            k_norm_slice<3><<<gN, blk, 0, stream>>>(a, wss, oss, ALPHA_S, inv_ns);
        }
        k_softmax_init<<<gN, blk, 0, stream>>>((const float4*)unary, (float4*)Q);
        for (int it = 0; it < 10; it++) {
            hipMemsetAsync(fAb, 0, (size_t)Vb * 4 * sizeof(float), stream);
            k_splat4<6><<<gN, blk, 0, stream>>>((const float4*)Q, wsb, osb, fAb);
            float* a = fAb; float* b = fBb;
            for (int j = 0; j < 6; j++) {
                k_blur4<<<gMb, blk, 0, stream>>>((const float4*)a, (float4*)b,
                                                 bnb + (size_t)j * Mb * 2, Mb);
                float* t = a; a = b; b = t;
            }
            float* finb = a;
            hipMemsetAsync(fAs, 0, (size_t)Vs * 4 * sizeof(float), stream);
            k_splat4<3><<<gN, blk, 0, stream>>>((const float4*)Q, wss, oss, fAs);
            float* as_ = fAs; float* bs_ = fBs;
            for (int j = 0; j < 3; j++) {
                k_blur4<<<gMs, blk, 0, stream>>>((const float4*)as_, (float4*)bs_,
                                                 bns + (size_t)j * Ms * 2, Ms);
                float* t = as_; as_ = bs_; bs_ = t;
            }
            float* fins = as_;
            k_slice_combine<<<gN, blk, 0, stream>>>((const float4*)unary,
                                                    (const float4*)finb, wsb, osb,
                                                    (const float4*)fins, wss, oss,
                                                    inv_nb, inv_ns, (float4*)Q);
        }
    }
}

// Round 2
// 952.353 us; speedup vs baseline: 1.1285x; 1.1285x over previous
//
#include <hip/hip_runtime.h>

#define NPIX (512 * 512)
#define BLK 256

#define TOTB (NPIX * 6)
#define TOTS (NPIX * 3)
#define TOTE (NPIX * 9)

typedef _Float16 h4 __attribute__((ext_vector_type(4)));

constexpr float ALPHA_B = 32.0f / 33.0f;   // 1/(1+2^-5)
constexpr float ALPHA_S = 0.8f;            // 1/(1+2^-2)
constexpr float BI_COMPAT = 10.0f;
constexpr float SP_COMPAT = 3.0f;

// 4-byte CSR entry: [31:18] = weight (14-bit fixed point, /16383), [17:0] = pixel id
__device__ __forceinline__ unsigned pack_ent(int n, float w) {
    float wc = fminf(fmaxf(w, 0.f), 1.f);
    unsigned iw = (unsigned)(wc * 16383.f + 0.5f);
    return (iw << 18) | (unsigned)n;
}
__device__ __forceinline__ int ent_pix(unsigned e) { return (int)(e & 0x3FFFFu); }
__device__ __forceinline__ float ent_w(unsigned e) {
    return (float)(e >> 18) * (1.0f / 16383.0f);
}

__device__ __forceinline__ float4 f4zero() { return make_float4(0.f, 0.f, 0.f, 0.f); }
__device__ __forceinline__ h4 h4zero() {
    h4 z; z.x = (_Float16)0.f; z.y = (_Float16)0.f; z.z = (_Float16)0.f; z.w = (_Float16)0.f;
    return z;
}

// ---------------- softmax init (fallback path) ----------------
__global__ void k_softmax_init(const float4* __restrict__ u, float4* __restrict__ Q) {
    int n = blockIdx.x * BLK + threadIdx.x;
    if (n >= NPIX) return;
    float4 uu = u[n];
    float l0 = -uu.x, l1 = -uu.y, l2 = -uu.z, l3 = -uu.w;
    float m = fmaxf(fmaxf(l0, l1), fmaxf(l2, l3));
    float e0 = expf(l0 - m), e1 = expf(l1 - m), e2 = expf(l2 - m), e3 = expf(l3 - m);
    float inv = 1.0f / (e0 + e1 + e2 + e3);
    Q[n] = make_float4(e0 * inv, e1 * inv, e2 * inv, e3 * inv);
}

// ---------------- fused linked-list build + softmax init ----------------
// ONE atomic per entry (atomicExch) — counts are implicit in the list.
// head is concatenated over both lattices: bilateral o in [0,Vb), spatial Vb+o.
// Entry ids: bilateral e = n*6+r in [0,TOTB); spatial e = TOTB + n*3+r.
// next[e] only read in k_compact (after dispatch boundary) -> no ordering needed.
__global__ void k_link_softmax(const int* __restrict__ osb, const int* __restrict__ oss,
                               int* __restrict__ head, int* __restrict__ next,
                               const float4* __restrict__ u, float4* __restrict__ Q,
                               int Vb) {
    int n = blockIdx.x * BLK + threadIdx.x;
    if (n >= NPIX) return;
    float4 uu = u[n];
    float l0 = -uu.x, l1 = -uu.y, l2 = -uu.z, l3 = -uu.w;
    float m = fmaxf(fmaxf(l0, l1), fmaxf(l2, l3));
    float e0 = expf(l0 - m), e1 = expf(l1 - m), e2 = expf(l2 - m), e3 = expf(l3 - m);
    float inv = 1.0f / (e0 + e1 + e2 + e3);
    Q[n] = make_float4(e0 * inv, e1 * inv, e2 * inv, e3 * inv);
#pragma unroll
    for (int r = 0; r < 6; r++) {
        int o = osb[n * 6 + r];
        int e = n * 6 + r;
        next[e] = atomicExch(&head[o], e);
    }
#pragma unroll
    for (int r = 0; r < 3; r++) {
        int o = Vb + oss[n * 3 + r];
        int e = TOTB + n * 3 + r;
        next[e] = atomicExch(&head[o], e);
    }
}

// ---------------- CSR compaction with block-level allocation ----------------
// Walk 1: count list length. Block LDS prefix-sum, ONE atomicAdd per block on a
// global cursor allocates the block's contiguous CSR range (vertex order within
// the ent array is irrelevant to the gather kernels; start/end are explicit).
// Walk 2: emit packed entries densely (coalesced-ish) + fused normalizer sums.
__global__ void k_compact(const int* __restrict__ head, const int* __restrict__ next,
                          const float* __restrict__ wsb, const float* __restrict__ wss,
                          unsigned* __restrict__ ent, int* __restrict__ start,
                          int* __restrict__ endv,
                          float* __restrict__ nB, float* __restrict__ nS,
                          int* __restrict__ cursor, int V, int Vb) {
    __shared__ int lds[BLK];
    __shared__ int sbase;
    int o = blockIdx.x * BLK + threadIdx.x;
    bool valid = o < V;
    int h = valid ? head[o] : -1;
    int len = 0;
    for (int e = h; e >= 0; e = next[e]) len++;
    lds[threadIdx.x] = len;
    __syncthreads();
    for (int off = 1; off < BLK; off <<= 1) {
        int t = ((int)threadIdx.x >= off) ? lds[threadIdx.x - off] : 0;
        __syncthreads();
        lds[threadIdx.x] += t;
        __syncthreads();
    }
    int incl = lds[threadIdx.x];
    if (threadIdx.x == BLK - 1) sbase = atomicAdd(cursor, incl);
    __syncthreads();
    if (!valid) return;
    int pos = sbase + incl - len;
    start[o] = pos;
    endv[o] = pos + len;
    float acc = 0.f;
    if (o < Vb) {
        for (int e = h; e >= 0; e = next[e]) {
            unsigned n = (unsigned)e / 6u;  // wsb is pixel-major: wsb[e] is the weight
            unsigned pe = pack_ent((int)n, wsb[e]);
            acc += ent_w(pe);
            ent[pos++] = pe;
        }
        nB[o] = acc;
    } else {
        for (int e = h; e >= 0; e = next[e]) {
            int ee = e - TOTB;
            unsigned pe = pack_ent(ee / 3, wss[ee]);
            acc += ent_w(pe);
            ent[pos++] = pe;
        }
        nS[o - Vb] = acc;
    }
}

// ---------------- gather-based splat (single concatenated CSR) ----------------
__global__ void k_gather4h_both(const unsigned* __restrict__ ent, const int* __restrict__ start,
                                const int* __restrict__ endv, int V, int Vb,
                                h4* __restrict__ tB, h4* __restrict__ tS,
                                const float4* __restrict__ Q) {
    int i = blockIdx.x * BLK + threadIdx.x;
    if (i >= V) return;
    int s = start[i];
    int e = endv[i];
    float ax = 0.f, ay = 0.f, az = 0.f, aw = 0.f;
    for (int k = s; k < e; k++) {
        unsigned en = ent[k];
        float w = ent_w(en);
        float4 q = Q[ent_pix(en)];
        ax += w * q.x; ay += w * q.y; az += w * q.z; aw += w * q.w;
    }
    h4 h;
    h.x = (_Float16)ax; h.y = (_Float16)ay; h.z = (_Float16)az; h.w = (_Float16)aw;
    if (i < Vb) tB[i] = h;
    else tS[i - Vb] = h;
}

// ---------------- blur ----------------
__global__ void k_blur1(const float* __restrict__ in, float* __restrict__ out,
                        const int* __restrict__ bn, int M) {
    int i = blockIdx.x * BLK + threadIdx.x;
    if (i > M) return;
    if (i == 0) { out[0] = 0.f; return; }
    int n1 = bn[(size_t)(i - 1) * 2 + 0];
    int n2 = bn[(size_t)(i - 1) * 2 + 1];
    out[i] = in[i] + 0.5f * (in[n1] + in[n2]);
}

__global__ void k_blur1_both(const float* __restrict__ inB, float* __restrict__ outB,
                             const int* __restrict__ bnB, int Mb,
                             const float* __restrict__ inS, float* __restrict__ outS,
                             const int* __restrict__ bnS, int Ms) {
    int i = blockIdx.x * BLK + threadIdx.x;
    const float* in; float* out; const int* bn; int M, idx;
    if (i <= Mb) { in = inB; out = outB; bn = bnB; M = Mb; idx = i; }
    else {
        idx = i - (Mb + 1);
        if (idx > Ms) return;
        in = inS; out = outS; bn = bnS; M = Ms;
    }
    if (idx == 0) { out[0] = 0.f; return; }
    int n1 = bn[(size_t)(idx - 1) * 2 + 0];
    int n2 = bn[(size_t)(idx - 1) * 2 + 1];
    out[idx] = in[idx] + 0.5f * (in[n1] + in[n2]);
}

__global__ void k_blur4h(const h4* __restrict__ in, h4* __restrict__ out,
                         const int* __restrict__ bn, int M) {
    int i = blockIdx.x * BLK + threadIdx.x;
    if (i > M) return;
    if (i == 0) { out[0] = h4zero(); return; }
    int n1 = bn[(size_t)(i - 1) * 2 + 0];
    int n2 = bn[(size_t)(i - 1) * 2 + 1];
    h4 a = in[i], b = in[n1], c = in[n2];
    h4 o;
    o.x = (_Float16)((float)a.x + 0.5f * ((float)b.x + (float)c.x));
    o.y = (_Float16)((float)a.y + 0.5f * ((float)b.y + (float)c.y));
    o.z = (_Float16)((float)a.z + 0.5f * ((float)b.z + (float)c.z));
    o.w = (_Float16)((float)a.w + 0.5f * ((float)b.w + (float)c.w));
    out[i] = o;
}

__global__ void k_blur4h_both(const h4* __restrict__ inB, h4* __restrict__ outB,
                              const int* __restrict__ bnB, int Mb,
                              const h4* __restrict__ inS, h4* __restrict__ outS,
                              const int* __restrict__ bnS, int Ms) {
    int i = blockIdx.x * BLK + threadIdx.x;
    const h4* in; h4* out; const int* bn; int M, idx;
    if (i <= Mb) { in = inB; out = outB; bn = bnB; M = Mb; idx = i; }
    else {
        idx = i - (Mb + 1);
        if (idx > Ms) return;
        in = inS; out = outS; bn = bnS; M = Ms;
    }
    if (idx == 0) { out[0] = h4zero(); return; }
    int n1 = bn[(size_t)(idx - 1) * 2 + 0];
    int n2 = bn[(size_t)(idx - 1) * 2 + 1];
    h4 a = in[idx], b = in[n1], c = in[n2];
    h4 o;
    o.x = (_Float16)((float)a.x + 0.5f * ((float)b.x + (float)c.x));
    o.y = (_Float16)((float)a.y + 0.5f * ((float)b.y + (float)c.y));
    o.z = (_Float16)((float)a.z + 0.5f * ((float)b.z + (float)c.z));
    o.w = (_Float16)((float)a.w + 0.5f * ((float)b.w + (float)c.w));
    out[idx] = o;
}

// ---------------- normalizer slice + weight prescale ----------------
__global__ void k_norm_prescale(const float* __restrict__ nTb, const float* __restrict__ wsb,
                                const int* __restrict__ osb,
                                const float* __restrict__ nTs, const float* __restrict__ wss,
                                const int* __restrict__ oss,
                                float* __restrict__ wsbp, float* __restrict__ wssp) {
    int n = blockIdx.x * BLK + threadIdx.x;
    if (n >= NPIX) return;
    float sb = 0.f;
#pragma unroll
    for (int r = 0; r < 6; r++) sb += wsb[n * 6 + r] * nTb[osb[n * 6 + r]];
    float cb = BI_COMPAT * ALPHA_B / (ALPHA_B * sb + 1e-20f);
#pragma unroll
    for (int r = 0; r < 6; r++) wsbp[n * 6 + r] = wsb[n * 6 + r] * cb;
    float ss = 0.f;
#pragma unroll
    for (int r = 0; r < 3; r++) ss += wss[n * 3 + r] * nTs[oss[n * 3 + r]];
    float cs = SP_COMPAT * ALPHA_S / (ALPHA_S * ss + 1e-20f);
#pragma unroll
    for (int r = 0; r < 3; r++) wssp[n * 3 + r] = wss[n * 3 + r] * cs;
}

// ---------------- fused slice + message + softmax ----------------
__global__ void k_slice_combine_h(const float4* __restrict__ u,
                                  const h4* __restrict__ tb, const float* __restrict__ wsbp,
                                  const int* __restrict__ osb,
                                  const h4* __restrict__ ts, const float* __restrict__ wssp,
                                  const int* __restrict__ oss,
                                  float4* __restrict__ Qout) {
    int n = blockIdx.x * BLK + threadIdx.x;
    if (n >= NPIX) return;
    float4 uu = u[n];
    float l0 = -uu.x, l1 = -uu.y, l2 = -uu.z, l3 = -uu.w;
#pragma unroll
    for (int r = 0; r < 6; r++) {
        float w = wsbp[n * 6 + r];
        h4 t = tb[osb[n * 6 + r]];
        l0 += w * (float)t.x; l1 += w * (float)t.y; l2 += w * (float)t.z; l3 += w * (float)t.w;
    }
#pragma unroll
    for (int r = 0; r < 3; r++) {
        float w = wssp[n * 3 + r];
        h4 t = ts[oss[n * 3 + r]];
        l0 += w * (float)t.x; l1 += w * (float)t.y; l2 += w * (float)t.z; l3 += w * (float)t.w;
    }
    float m = fmaxf(fmaxf(l0, l1), fmaxf(l2, l3));
    float e0 = expf(l0 - m), e1 = expf(l1 - m), e2 = expf(l2 - m), e3 = expf(l3 - m);
    float inv = 1.0f / (e0 + e1 + e2 + e3);
    Qout[n] = make_float4(e0 * inv, e1 * inv, e2 * inv, e3 * inv);
}

// ---------------- fallback (fp32 atomic splat path) ----------------
template <int D1>
__global__ void k_splat1(const float* __restrict__ ws, const int* __restrict__ os,
                         float* __restrict__ table) {
    int n = blockIdx.x * BLK + threadIdx.x;
    if (n >= NPIX) return;
#pragma unroll
    for (int r = 0; r < D1; r++) atomicAdd(&table[os[n * D1 + r]], ws[n * D1 + r]);
}

template <int D1>
__global__ void k_splat4(const float4* __restrict__ Q, const float* __restrict__ ws,
                         const int* __restrict__ os, float* __restrict__ table) {
    int n = blockIdx.x * BLK + threadIdx.x;
    if (n >= NPIX) return;
    float4 q = Q[n];
#pragma unroll
    for (int r = 0; r < D1; r++) {
        float w = ws[n * D1 + r];
        int o = os[n * D1 + r];
        float* t = table + 4 * (size_t)o;
        atomicAdd(t + 0, q.x * w);
        atomicAdd(t + 1, q.y * w);
        atomicAdd(t + 2, q.z * w);
        atomicAdd(t + 3, q.w * w);
    }
}

__global__ void k_blur4(const float4* __restrict__ in, float4* __restrict__ out,
                        const int* __restrict__ bn, int M) {
    int i = blockIdx.x * BLK + threadIdx.x;
    if (i > M) return;
    if (i == 0) { out[0] = f4zero(); return; }
    int n1 = bn[(size_t)(i - 1) * 2 + 0];
    int n2 = bn[(size_t)(i - 1) * 2 + 1];
    float4 a = in[i], b = in[n1], c = in[n2];
    out[i] = make_float4(a.x + 0.5f * (b.x + c.x), a.y + 0.5f * (b.y + c.y),
                         a.z + 0.5f * (b.z + c.z), a.w + 0.5f * (b.w + c.w));
}

template <int D1>
__global__ void k_norm_slice(const float* __restrict__ table, const float* __restrict__ ws,
                             const int* __restrict__ os, float alpha,
                             float* __restrict__ inv_out) {
    int n = blockIdx.x * BLK + threadIdx.x;
    if (n >= NPIX) return;
    float s = 0.f;
#pragma unroll
    for (int r = 0; r < D1; r++) s += ws[n * D1 + r] * table[os[n * D1 + r]];
    inv_out[n] = 1.0f / (alpha * s + 1e-20f);
}

__global__ void k_slice_combine(const float4* __restrict__ u,
                                const float4* __restrict__ tb, const float* __restrict__ wsb,
                                const int* __restrict__ osb,
                                const float4* __restrict__ ts, const float* __restrict__ wss,
                                const int* __restrict__ oss,
                                const float* __restrict__ inv_nb,
                                const float* __restrict__ inv_ns,
                                float4* __restrict__ Qout) {
    int n = blockIdx.x * BLK + threadIdx.x;
    if (n >= NPIX) return;
    float4 ab = f4zero();
#pragma unroll
    for (int r = 0; r < 6; r++) {
        float w = wsb[n * 6 + r];
        float4 t = tb[osb[n * 6 + r]];
        ab.x += w * t.x; ab.y += w * t.y; ab.z += w * t.z; ab.w += w * t.w;
    }
    float4 as = f4zero();
#pragma unroll
    for (int r = 0; r < 3; r++) {
        float w = wss[n * 3 + r];
        float4 t = ts[oss[n * 3 + r]];
        as.x += w * t.x; as.y += w * t.y; as.z += w * t.z; as.w += w * t.w;
    }
    float cb = BI_COMPAT * ALPHA_B * inv_nb[n];
    float cs = SP_COMPAT * ALPHA_S * inv_ns[n];
    float4 uu = u[n];
    float l0 = -uu.x + cb * ab.x + cs * as.x;
    float l1 = -uu.y + cb * ab.y + cs * as.y;
    float l2 = -uu.z + cb * ab.z + cs * as.z;
    float l3 = -uu.w + cb * ab.w + cs * as.w;
    float m = fmaxf(fmaxf(l0, l1), fmaxf(l2, l3));
    float e0 = expf(l0 - m), e1 = expf(l1 - m), e2 = expf(l2 - m), e3 = expf(l3 - m);
    float inv = 1.0f / (e0 + e1 + e2 + e3);
    Qout[n] = make_float4(e0 * inv, e1 * inv, e2 * inv, e3 * inv);
}

extern "C" void kernel_launch(void* const* d_in, const int* in_sizes, int n_in,
                              void* d_out, int out_size, void* d_ws, size_t ws_size,
                              hipStream_t stream) {
    const float* unary = (const float*)d_in[0];
    const float* wsb   = (const float*)d_in[1];
    const int*   osb   = (const int*)d_in[2];
    const int*   bnb   = (const int*)d_in[3];
    const float* wss   = (const float*)d_in[5];
    const int*   oss   = (const int*)d_in[6];
    const int*   bns   = (const int*)d_in[7];
    const int Mb = in_sizes[3] / 12;   // bn_b is (6, Mb, 2)
    const int Ms = in_sizes[7] / 6;    // bn_s is (3, Ms, 2)
    const int Vb = Mb + 1, Vs = Ms + 1;
    const int V = Vb + Vs;

    float* Q = (float*)d_out;  // N x 4, final value IS the output

    char* p = (char*)d_ws;
    auto alloc = [&](size_t nbytes) -> void* {
        void* r = (void*)p;
        p += (nbytes + 15) & ~(size_t)15;
        return r;
    };
    h4*   tAb  = (h4*)alloc((size_t)Vb * 8);
    h4*   tBb  = (h4*)alloc((size_t)Vb * 8);
    h4*   tAs  = (h4*)alloc((size_t)Vs * 8);
    h4*   tBs  = (h4*)alloc((size_t)Vs * 8);
    float* nAb = (float*)alloc((size_t)Vb * 4);
    float* nBb = (float*)alloc((size_t)Vb * 4);
    float* nAs = (float*)alloc((size_t)Vs * 4);
    float* nBs = (float*)alloc((size_t)Vs * 4);
    // wsbp (6N floats) and wssp (3N floats) are contiguous (6N*4 is 16B-aligned);
    // the 9N-int `next` array aliases them: next is dead before k_norm_prescale
    // writes wsbp/wssp, and wsbp/wssp are only read after that.
    float* wsbp = (float*)alloc((size_t)NPIX * 6 * 4);
    float* wssp = (float*)alloc((size_t)NPIX * 3 * 4);
    int*   next = (int*)wsbp;
    int*  start = (int*)alloc((size_t)V * 4);
    int*  endv  = (int*)alloc((size_t)V * 4);
    int*  head  = (int*)alloc((size_t)V * 4);
    unsigned* ent = (unsigned*)alloc((size_t)TOTE * 4);
    int*  cursor = (int*)alloc(16);
    size_t need = (size_t)(p - (char*)d_ws);
    bool use_gather = need <= ws_size;

    dim3 blk(BLK);
    dim3 gN((NPIX + BLK - 1) / BLK);
    dim3 gVb((Vb + BLK - 1) / BLK);
    dim3 gV((V + BLK - 1) / BLK);

    if (use_gather) {
        // ---- build CSR via linked-list inversion + self-allocating compaction ----
        hipMemsetAsync(head, 0xFF, (size_t)V * 4, stream);  // -1 sentinel
        hipMemsetAsync(cursor, 0, 16, stream);
        k_link_softmax<<<gN, blk, 0, stream>>>(osb, oss, head, next,
                                               (const float4*)unary, (float4*)Q, Vb);
        k_compact<<<gV, blk, 0, stream>>>(head, next, wsb, wss, ent, start, endv,
                                          nAb, nAs, cursor, V, Vb);

        // ---- normalizer blur chain (C=1, fp32), then prescale slice weights ----
        {
            float* a = nAb; float* b = nBb;
            float* as_ = nAs; float* bs_ = nBs;
            for (int j = 0; j < 3; j++) {
                k_blur1_both<<<gV, blk, 0, stream>>>(a, b, bnb + (size_t)j * Mb * 2, Mb,
                                                     as_, bs_, bns + (size_t)j * Ms * 2, Ms);
                float* t = a; a = b; b = t;
                t = as_; as_ = bs_; bs_ = t;
            }
            for (int j = 3; j < 6; j++) {
                k_blur1<<<gVb, blk, 0, stream>>>(a, b, bnb + (size_t)j * Mb * 2, Mb);
                float* t = a; a = b; b = t;
            }
            // bilateral final in a, spatial final in as_
            k_norm_prescale<<<gN, blk, 0, stream>>>(a, wsb, osb, as_, wss, oss, wsbp, wssp);
        }

        // ---- 10 mean-field iterations ----
        for (int it = 0; it < 10; it++) {
            k_gather4h_both<<<gV, blk, 0, stream>>>(ent, start, endv, V, Vb, tAb, tAs,
                                                    (const float4*)Q);
            h4* a = tAb; h4* b = tBb;
            h4* as_ = tAs; h4* bs_ = tBs;
            for (int j = 0; j < 3; j++) {
                k_blur4h_both<<<gV, blk, 0, stream>>>(a, b, bnb + (size_t)j * Mb * 2, Mb,
                                                      as_, bs_, bns + (size_t)j * Ms * 2, Ms);
                h4* t = a; a = b; b = t;
                t = as_; as_ = bs_; bs_ = t;
            }
            for (int j = 3; j < 6; j++) {
                k_blur4h<<<gVb, blk, 0, stream>>>(a, b, bnb + (size_t)j * Mb * 2, Mb);
                h4* t = a; a = b; b = t;
            }
            // bilateral final in a (= tAb), spatial final in as_ (= tBs)
            k_slice_combine_h<<<gN, blk, 0, stream>>>((const float4*)unary,
                                                      a, wsbp, osb, as_, wssp, oss,
                                                      (float4*)Q);
        }
    } else {
        // ---- fallback: fp32 atomic splat path ----
        char* q = (char*)d_ws;
        auto alloc2 = [&](size_t nbytes) -> void* {
            void* r = (void*)q;
            q += (nbytes + 15) & ~(size_t)15;
            return r;
        };
        float* fAb = (float*)alloc2((size_t)Vb * 4 * sizeof(float));
        float* fBb = (float*)alloc2((size_t)Vb * 4 * sizeof(float));
        float* fAs = (float*)alloc2((size_t)Vs * 4 * sizeof(float));
        float* fBs = (float*)alloc2((size_t)Vs * 4 * sizeof(float));
        float* inv_nb = (float*)alloc2(NPIX * sizeof(float));
        float* inv_ns = (float*)alloc2(NPIX * sizeof(float));
        dim3 gMb((Mb + 1 + BLK - 1) / BLK);
        dim3 gMs((Ms + 1 + BLK - 1) / BLK);

        hipMemsetAsync(fAb, 0, (size_t)Vb * sizeof(float), stream);
        k_splat1<6><<<gN, blk, 0, stream>>>(wsb, osb, fAb);
        {
            float* a = fAb; float* b = fBb;
            for (int j = 0; j < 6; j++) {
                k_blur1<<<gMb, blk, 0, stream>>>(a, b, bnb + (size_t)j * Mb * 2, Mb);
                float* t = a; a = b; b = t;
            }
            k_norm_slice<6><<<gN, blk, 0, stream>>>(a, wsb, osb, ALPHA_B, inv_nb);
        }
        hipMemsetAsync(fAs, 0, (size_t)Vs * sizeof(float), stream);
        k_splat1<3><<<gN, blk, 0, stream>>>(wss, oss, fAs);
        {
            float* a = fAs; float* b = fBs;
            for (int j = 0; j < 3; j++) {
                k_blur1<<<gMs, blk, 0, stream>>>(a, b, bns + (size_t)j * Ms * 2, Ms);
                float* t = a; a = b; b = t;
            }
            k_norm_slice<3><<<gN, blk, 0, stream>>>(a, wss, oss, ALPHA_S, inv_ns);
        }
        k_softmax_init<<<gN, blk, 0, stream>>>((const float4*)unary, (float4*)Q);
        for (int it = 0; it < 10; it++) {
            hipMemsetAsync(fAb, 0, (size_t)Vb * 4 * sizeof(float), stream);
            k_splat4<6><<<gN, blk, 0, stream>>>((const float4*)Q, wsb, osb, fAb);
            float* a = fAb; float* b = fBb;
            for (int j = 0; j < 6; j++) {
                k_blur4<<<gMb, blk, 0, stream>>>((const float4*)a, (float4*)b,
                                                 bnb + (size_t)j * Mb * 2, Mb);
                float* t = a; a = b; b = t;
            }
            float* finb = a;
            hipMemsetAsync(fAs, 0, (size_t)Vs * 4 * sizeof(float), stream);
            k_splat4<3><<<gN, blk, 0, stream>>>((const float4*)Q, wss, oss, fAs);
            float* as_ = fAs; float* bs_ = fBs;
            for (int j = 0; j < 3; j++) {
                k_blur4<<<gMs, blk, 0, stream>>>((const float4*)as_, (float4*)bs_,
                                                 bns + (size_t)j * Ms * 2, Ms);
                float* t = as_; as_ = bs_; bs_ = t;
            }
            float* fins = as_;
            k_slice_combine<<<gN, blk, 0, stream>>>((const float4*)unary,
                                                    (const float4*)finb, wsb, osb,
                                                    (const float4*)fins, wss, oss,
                                                    inv_nb, inv_ns, (float4*)Q);
        }
    }
}